// Round 3
// baseline (463.849 us; speedup 1.0000x reference)
//
#include <hip/hip_runtime.h>
#include <hip/hip_bf16.h>
#include <math.h>

// ---------------------------------------------------------------------------
// VariationalGATEncoder round 3:
//  - alpha (normalized softmax weight) precomputed per edge by a thread-per-
//    node kernel -> aggregate kernels are pure weighted gathers (no shfl
//    reductions / exp in the hot loop).
//  - aggregate processes 2 edges per wave iteration (32 lanes x 16B each):
//    half the load instructions, ~30% fewer VALU insts per edge.
//  - attention scores fused into the GEMM epilogue (fp32 acc dot a-vector +
//    atomicAdd per row) -> scores kernels and their 51MB of re-reads removed.
// ---------------------------------------------------------------------------

#define NNODES 50000

typedef __attribute__((ext_vector_type(8))) short bf16x8;
typedef __attribute__((ext_vector_type(4))) float f32x4;

__device__ inline float bf2f(unsigned short u) {
    return __uint_as_float(((unsigned int)u) << 16);
}
__device__ inline unsigned short f2bf(float f) {
    unsigned int i = __float_as_uint(f);
    unsigned int r = i + 0x7fffu + ((i >> 16) & 1u);   // RNE
    return (unsigned short)(r >> 16);
}

// ---------------- converts ----------------

__global__ void f32_to_bf16_kernel(const float* __restrict__ in, unsigned short* __restrict__ out, int n4) {
    int i = blockIdx.x * blockDim.x + threadIdx.x;
    if (i < n4) {
        float4 v = ((const float4*)in)[i];
        ushort4 o;
        o.x = f2bf(v.x); o.y = f2bf(v.y); o.z = f2bf(v.z); o.w = f2bf(v.w);
        ((ushort4*)out)[i] = o;
    }
}

__global__ void transpose_w_kernel(const float* __restrict__ W, unsigned short* __restrict__ Wt, int K, int Nc) {
    int n = blockIdx.x, k = threadIdx.x;
    Wt[(size_t)n * K + k] = f2bf(W[(size_t)k * Nc + n]);
}

__global__ void transpose_wcat_kernel(const float* __restrict__ Wmu, const float* __restrict__ Wls,
                                      unsigned short* __restrict__ Wt) {
    int n = blockIdx.x, k = threadIdx.x;
    float v = (n < 128) ? Wmu[(size_t)k * 128 + n] : Wls[(size_t)k * 128 + (n - 128)];
    Wt[(size_t)n * 256 + k] = f2bf(v);
}

// ---------------- CSR build ----------------

__global__ void count_edges(const int* __restrict__ dst, int E, int* __restrict__ cnt) {
    int e = blockIdx.x * blockDim.x + threadIdx.x;
    if (e < E) atomicAdd(&cnt[dst[e]], 1);
}

__global__ void scan_partial(const int* __restrict__ cnt, int* __restrict__ row_start,
                             int* __restrict__ bsum, int N) {
    __shared__ int wsum[16];
    int t = threadIdx.x;
    int gi = blockIdx.x * 1024 + t;
    int lane = t & 63, wid = t >> 6;
    int v = (gi < N) ? cnt[gi] : 0;
    int x = v;
    for (int off = 1; off < 64; off <<= 1) {
        int u = __shfl_up(x, off);
        if (lane >= off) x += u;
    }
    if (lane == 63) wsum[wid] = x;
    __syncthreads();
    if (wid == 0) {
        int s = (lane < 16) ? wsum[lane] : 0;
        for (int off = 1; off < 16; off <<= 1) {
            int u = __shfl_up(s, off);
            if (lane >= off) s += u;
        }
        if (lane < 16) wsum[lane] = s;
    }
    __syncthreads();
    int waveoff = (wid == 0) ? 0 : wsum[wid - 1];
    if (gi < N) row_start[gi] = waveoff + x - v;
    if (t == 1023) bsum[blockIdx.x] = waveoff + x;
}

__global__ void scan_bsum(int* __restrict__ bsum, int nb) {
    int lane = threadIdx.x;
    int v = (lane < nb) ? bsum[lane] : 0;
    int x = v;
    for (int off = 1; off < 64; off <<= 1) {
        int u = __shfl_up(x, off);
        if (lane >= off) x += u;
    }
    if (lane < nb) bsum[lane] = x - v;
}

__global__ void scan_add(int* __restrict__ row_start, const int* __restrict__ bsum, int N, int E) {
    int gi = blockIdx.x * 1024 + threadIdx.x;
    if (gi < N) row_start[gi] += bsum[blockIdx.x];
    if (gi == 0) row_start[N] = E;
}

__global__ void scatter_edges(const int* __restrict__ src, const int* __restrict__ dst, int E,
                              const int* __restrict__ row_start, int* __restrict__ cursor,
                              int* __restrict__ sperm) {
    int e = blockIdx.x * blockDim.x + threadIdx.x;
    if (e < E) {
        int d = dst[e];
        int pos = row_start[d] + atomicAdd(&cursor[d], 1);
        sperm[pos] = src[e];
    }
}

// ---------------- bf16 MFMA GEMM with fused score epilogue ----------------
// C[M,256](bf16) = A[M,256](bf16) @ Bt[256,256]^T. blockIdx.y selects a
// 128-col half; scores for that half's head are accumulated via atomicAdd:
//   sS[m] += sum_n acc[m][n]*aS[n],  sD[m] += sum_n acc[m][n]*aD[n]

__global__ __launch_bounds__(256) void mfma_gemm_sc(const unsigned short* __restrict__ A,
                                                    const unsigned short* __restrict__ Bt,
                                                    unsigned short* __restrict__ C_,
                                                    int M, int K, int Cout,
                                                    const float* __restrict__ aS0, const float* __restrict__ aD0,
                                                    const float* __restrict__ aS1, const float* __restrict__ aD1,
                                                    float* __restrict__ sS0, float* __restrict__ sD0,
                                                    float* __restrict__ sS1, float* __restrict__ sD1) {
    __shared__ __align__(16) unsigned short As[128 * 40];
    __shared__ __align__(16) unsigned short Bs[128 * 40];
    int t = threadIdx.x;
    int lane = t & 63, w = t >> 6;
    int wm = w & 1, wn = w >> 1;
    int l15 = lane & 15, quad = lane >> 4;
    int mbase = blockIdx.x * 128, nbase = blockIdx.y * 128;

    f32x4 acc[4][4];
    const f32x4 zero = {0.f, 0.f, 0.f, 0.f};
#pragma unroll
    for (int mt = 0; mt < 4; mt++)
#pragma unroll
        for (int nt = 0; nt < 4; nt++) acc[mt][nt] = zero;

    for (int k0 = 0; k0 < K; k0 += 32) {
#pragma unroll
        for (int i = t; i < 512; i += 256) {
            int row = i >> 2, seg = i & 3;
            int gr = mbase + row;
            float4 va = make_float4(0.f, 0.f, 0.f, 0.f);
            if (gr < M) va = *(const float4*)(A + (size_t)gr * K + k0 + seg * 8);
            *(float4*)(&As[row * 40 + seg * 8]) = va;
            float4 vb = *(const float4*)(Bt + (size_t)(nbase + row) * K + k0 + seg * 8);
            *(float4*)(&Bs[row * 40 + seg * 8]) = vb;
        }
        __syncthreads();
        bf16x8 af[4], bfr[4];
#pragma unroll
        for (int mt = 0; mt < 4; mt++)
            af[mt] = *(const bf16x8*)(&As[(wm * 64 + mt * 16 + l15) * 40 + quad * 8]);
#pragma unroll
        for (int nt = 0; nt < 4; nt++)
            bfr[nt] = *(const bf16x8*)(&Bs[(wn * 64 + nt * 16 + l15) * 40 + quad * 8]);
#pragma unroll
        for (int mt = 0; mt < 4; mt++)
#pragma unroll
            for (int nt = 0; nt < 4; nt++)
                acc[mt][nt] = __builtin_amdgcn_mfma_f32_16x16x32_bf16(af[mt], bfr[nt], acc[mt][nt], 0, 0, 0);
        __syncthreads();
    }

    // C store (C/D layout: col=lane&15, row=quad*4+reg)
#pragma unroll
    for (int mt = 0; mt < 4; mt++)
#pragma unroll
        for (int nt = 0; nt < 4; nt++)
#pragma unroll
            for (int r = 0; r < 4; r++) {
                int m = mbase + wm * 64 + mt * 16 + quad * 4 + r;
                int n = nbase + wn * 64 + nt * 16 + l15;
                if (m < M) C_[(size_t)m * Cout + n] = f2bf(acc[mt][nt][r]);
            }

    // fused scores
    const float* aS = (blockIdx.y == 0) ? aS0 : aS1;
    const float* aD = (blockIdx.y == 0) ? aD0 : aD1;
    float* sS = (blockIdx.y == 0) ? sS0 : sS1;
    float* sD = (blockIdx.y == 0) ? sD0 : sD1;
    float as_[4], ad_[4];
#pragma unroll
    for (int nt = 0; nt < 4; nt++) {
        int nl = wn * 64 + nt * 16 + l15;
        as_[nt] = aS[nl];
        ad_[nt] = aD[nl];
    }
#pragma unroll
    for (int mt = 0; mt < 4; mt++)
#pragma unroll
        for (int r = 0; r < 4; r++) {
            float ps = 0.f, pd = 0.f;
#pragma unroll
            for (int nt = 0; nt < 4; nt++) {
                ps += acc[mt][nt][r] * as_[nt];
                pd += acc[mt][nt][r] * ad_[nt];
            }
            for (int off = 1; off < 16; off <<= 1) {
                ps += __shfl_xor(ps, off);
                pd += __shfl_xor(pd, off);
            }
            if (l15 == 0) {
                int m = mbase + wm * 64 + mt * 16 + quad * 4 + r;
                if (m < M) {
                    atomicAdd(&sS[m], ps);
                    atomicAdd(&sD[m], pd);
                }
            }
        }
}

// ---------------- alpha precompute (thread per node, 3 passes) ----------------

__global__ void alpha_l1_kernel(const float* __restrict__ ssrc, const float* __restrict__ sdst,
                                const int* __restrict__ row_start, const int* __restrict__ sperm,
                                float* __restrict__ alpha, int N) {
    int n = blockIdx.x * blockDim.x + threadIdx.x;
    if (n >= N) return;
    int b = row_start[n], e = row_start[n + 1];
    float sd = sdst[n];
    float m = -INFINITY;
    for (int j = b; j < e; j++) {
        float t = ssrc[sperm[j]] + sd;
        t = (t > 0.f) ? t : 0.2f * t;
        alpha[j] = t;
        m = fmaxf(m, t);
    }
    float z = 0.f;
    for (int j = b; j < e; j++) {
        float p = __expf(alpha[j] - m);
        alpha[j] = p;
        z += p;
    }
    float inv = 1.f / (z + 1e-16f);
    for (int j = b; j < e; j++) alpha[j] *= inv;
}

__global__ void alpha_cat_kernel(const float* __restrict__ sms, const float* __restrict__ smd,
                                 const float* __restrict__ sls, const float* __restrict__ sld,
                                 const int* __restrict__ row_start, const int* __restrict__ sperm,
                                 float* __restrict__ amu, float* __restrict__ als, int N) {
    int n = blockIdx.x * blockDim.x + threadIdx.x;
    if (n >= N) return;
    int b = row_start[n], e = row_start[n + 1];
    float sdm = smd[n], sdl = sld[n];
    float mM = -INFINITY, mL = -INFINITY;
    for (int j = b; j < e; j++) {
        int s = sperm[j];
        float tM = sms[s] + sdm;
        tM = (tM > 0.f) ? tM : 0.2f * tM;
        amu[j] = tM;
        mM = fmaxf(mM, tM);
        float tL = sls[s] + sdl;
        tL = (tL > 0.f) ? tL : 0.2f * tL;
        als[j] = tL;
        mL = fmaxf(mL, tL);
    }
    float zM = 0.f, zL = 0.f;
    for (int j = b; j < e; j++) {
        float pM = __expf(amu[j] - mM);
        amu[j] = pM;
        zM += pM;
        float pL = __expf(als[j] - mL);
        als[j] = pL;
        zL += pL;
    }
    float invM = 1.f / (zM + 1e-16f);
    float invL = 1.f / (zL + 1e-16f);
    for (int j = b; j < e; j++) {
        amu[j] *= invM;
        als[j] *= invL;
    }
}

// ---------------- aggregation: pure weighted gather ----------------
// One wave per node; 2 edges per iteration: 32 lanes x 16B (8 bf16 ch) each.

__device__ inline void cvt2(unsigned int d, float& lo, float& hi) {
    lo = __uint_as_float(d << 16);
    hi = __uint_as_float(d & 0xffff0000u);
}

__global__ __launch_bounds__(256) void aggregate_l1(const unsigned short* __restrict__ h,
                                                    const float* __restrict__ alpha,
                                                    const int* __restrict__ row_start,
                                                    const int* __restrict__ sperm,
                                                    const float* __restrict__ bias,
                                                    unsigned short* __restrict__ out, int N) {
    int wave = threadIdx.x >> 6, lane = threadIdx.x & 63;
    int node = blockIdx.x * 4 + wave;
    if (node >= N) return;
    int begin = row_start[node], end = row_start[node + 1];
    int half = lane >> 5, l31 = lane & 31;
    float acc[8];
#pragma unroll
    for (int u = 0; u < 8; u++) acc[u] = 0.f;

    for (int j0 = begin; j0 < end; j0 += 64) {
        int idx = j0 + lane;
        bool v = idx < end;
        float a_l = v ? alpha[idx] : 0.f;
        int s_l = v ? sperm[idx] : 0;
        int cnt = min(64, end - j0);
        int iters = (cnt + 1) >> 1;
        for (int i = 0; i < iters; i++) {
            int t = 2 * i + half;
            int tc = min(t, cnt - 1);
            float w = __shfl(a_l, tc);
            if (t >= cnt) w = 0.f;
            int s = __shfl(s_l, tc);
            uint4 d = *(const uint4*)(h + (size_t)s * 256 + l31 * 8);
            float f0, f1, f2, f3, f4, f5, f6, f7;
            cvt2(d.x, f0, f1); cvt2(d.y, f2, f3); cvt2(d.z, f4, f5); cvt2(d.w, f6, f7);
            acc[0] += w * f0; acc[1] += w * f1; acc[2] += w * f2; acc[3] += w * f3;
            acc[4] += w * f4; acc[5] += w * f5; acc[6] += w * f6; acc[7] += w * f7;
        }
    }
#pragma unroll
    for (int u = 0; u < 8; u++) acc[u] += __shfl_xor(acc[u], 32);
    if (half == 0) {
        int c = l31 * 8;
        float4 b0 = *(const float4*)(bias + c);
        float4 b1 = *(const float4*)(bias + c + 4);
        float o0 = fmaxf(acc[0] + b0.x, 0.f), o1 = fmaxf(acc[1] + b0.y, 0.f);
        float o2 = fmaxf(acc[2] + b0.z, 0.f), o3 = fmaxf(acc[3] + b0.w, 0.f);
        float o4 = fmaxf(acc[4] + b1.x, 0.f), o5 = fmaxf(acc[5] + b1.y, 0.f);
        float o6 = fmaxf(acc[6] + b1.z, 0.f), o7 = fmaxf(acc[7] + b1.w, 0.f);
        uint4 st;
        st.x = ((unsigned)f2bf(o1) << 16) | f2bf(o0);
        st.y = ((unsigned)f2bf(o3) << 16) | f2bf(o2);
        st.z = ((unsigned)f2bf(o5) << 16) | f2bf(o4);
        st.w = ((unsigned)f2bf(o7) << 16) | f2bf(o6);
        *(uint4*)(out + (size_t)node * 256 + c) = st;
    }
}

// hcat row = [mu 128ch | ls 128ch]; lane l31<16 owns mu channels, else ls.
__global__ __launch_bounds__(256) void aggregate_cat(const unsigned short* __restrict__ hcat,
                                                     const float* __restrict__ amu,
                                                     const float* __restrict__ als,
                                                     const int* __restrict__ row_start,
                                                     const int* __restrict__ sperm,
                                                     const float* __restrict__ b_mu,
                                                     const float* __restrict__ b_ls,
                                                     float* __restrict__ out_mu,
                                                     float* __restrict__ out_ls, int N) {
    int wave = threadIdx.x >> 6, lane = threadIdx.x & 63;
    int node = blockIdx.x * 4 + wave;
    if (node >= N) return;
    int begin = row_start[node], end = row_start[node + 1];
    int half = lane >> 5, l31 = lane & 31;
    bool isMu = l31 < 16;
    float acc[8];
#pragma unroll
    for (int u = 0; u < 8; u++) acc[u] = 0.f;

    for (int j0 = begin; j0 < end; j0 += 64) {
        int idx = j0 + lane;
        bool v = idx < end;
        float am_l = v ? amu[idx] : 0.f;
        float al_l = v ? als[idx] : 0.f;
        int s_l = v ? sperm[idx] : 0;
        int cnt = min(64, end - j0);
        int iters = (cnt + 1) >> 1;
        for (int i = 0; i < iters; i++) {
            int t = 2 * i + half;
            int tc = min(t, cnt - 1);
            float wm = __shfl(am_l, tc);
            float wl = __shfl(al_l, tc);
            float w = isMu ? wm : wl;
            if (t >= cnt) w = 0.f;
            int s = __shfl(s_l, tc);
            uint4 d = *(const uint4*)(hcat + (size_t)s * 256 + l31 * 8);
            float f0, f1, f2, f3, f4, f5, f6, f7;
            cvt2(d.x, f0, f1); cvt2(d.y, f2, f3); cvt2(d.z, f4, f5); cvt2(d.w, f6, f7);
            acc[0] += w * f0; acc[1] += w * f1; acc[2] += w * f2; acc[3] += w * f3;
            acc[4] += w * f4; acc[5] += w * f5; acc[6] += w * f6; acc[7] += w * f7;
        }
    }
#pragma unroll
    for (int u = 0; u < 8; u++) acc[u] += __shfl_xor(acc[u], 32);
    if (half == 0) {
        int c = isMu ? (l31 * 8) : (l31 * 8 - 128);
        const float* bp = isMu ? b_mu : b_ls;
        float* op = isMu ? out_mu : out_ls;
        float4 b0 = *(const float4*)(bp + c);
        float4 b1 = *(const float4*)(bp + c + 4);
        float4 v0 = make_float4(acc[0] + b0.x, acc[1] + b0.y, acc[2] + b0.z, acc[3] + b0.w);
        float4 v1 = make_float4(acc[4] + b1.x, acc[5] + b1.y, acc[6] + b1.z, acc[7] + b1.w);
        *(float4*)(op + (size_t)node * 128 + c) = v0;
        *(float4*)(op + (size_t)node * 128 + c + 4) = v1;
    }
}

// ---------------- launch ----------------

extern "C" void kernel_launch(void* const* d_in, const int* in_sizes, int n_in,
                              void* d_out, int out_size, void* d_ws, size_t ws_size,
                              hipStream_t stream) {
    const int N = NNODES;
    const float* x      = (const float*)d_in[0];
    const int*   ei     = (const int*)d_in[1];
    const int    E      = in_sizes[1] / 2;
    const int*   src    = ei;
    const int*   dst    = ei + E;
    const float* W1     = (const float*)d_in[2];
    const float* a_src1 = (const float*)d_in[3];
    const float* a_dst1 = (const float*)d_in[4];
    const float* b1     = (const float*)d_in[5];
    const float* W_mu   = (const float*)d_in[6];
    const float* a_src_mu = (const float*)d_in[7];
    const float* a_dst_mu = (const float*)d_in[8];
    const float* b_mu   = (const float*)d_in[9];
    const float* W_ls   = (const float*)d_in[10];
    const float* a_src_ls = (const float*)d_in[11];
    const float* a_dst_ls = (const float*)d_in[12];
    const float* b_ls   = (const float*)d_in[13];

    const size_t NM = (size_t)N * 256;

    // workspace layout
    char* w = (char*)d_ws;
    unsigned short* xb   = (unsigned short*)w;  w += NM * 2;
    unsigned short* hlin = (unsigned short*)w;  w += NM * 2;
    unsigned short* h    = (unsigned short*)w;  w += NM * 2;
    unsigned short* hcat = (unsigned short*)w;  w += NM * 2;
    unsigned short* W1t  = (unsigned short*)w;  w += 256 * 256 * 2;
    unsigned short* Wct  = (unsigned short*)w;  w += 256 * 256 * 2;
    float* s1s = (float*)w;  w += N * 4;        // 6 contiguous score arrays
    float* s1d = (float*)w;  w += N * 4;
    float* sms = (float*)w;  w += N * 4;
    float* smd = (float*)w;  w += N * 4;
    float* sls = (float*)w;  w += N * 4;
    float* sld = (float*)w;  w += N * 4;
    float* alpha1 = (float*)w;  w += (size_t)E * 4;
    float* amu    = (float*)w;  w += (size_t)E * 4;
    float* als    = (float*)w;  w += (size_t)E * 4;
    int* row_start = (int*)w;  w += (N + 1) * 4;
    int* cnt = (int*)w;        w += N * 4;
    int* bsum = (int*)w;       w += 64 * 4;
    int* sperm = (int*)w;      w += (size_t)E * 4;

    const int egrid = (E + 255) / 256;
    const int ngrid4 = (N + 3) / 4;               // 12500
    const int ngrid256 = (N + 255) / 256;         // 196
    const int nb1024 = (N + 1023) / 1024;         // 49
    const int mtiles = (N + 127) / 128;           // 391

    // ---- converts ----
    f32_to_bf16_kernel<<<(int)((NM / 4 + 255) / 256), 256, 0, stream>>>(x, xb, (int)(NM / 4));
    transpose_w_kernel<<<256, 256, 0, stream>>>(W1, W1t, 256, 256);
    transpose_wcat_kernel<<<256, 256, 0, stream>>>(W_mu, W_ls, Wct);

    // ---- CSR build ----
    hipMemsetAsync(cnt, 0, N * sizeof(int), stream);
    count_edges<<<egrid, 256, 0, stream>>>(dst, E, cnt);
    scan_partial<<<nb1024, 1024, 0, stream>>>(cnt, row_start, bsum, N);
    scan_bsum<<<1, 64, 0, stream>>>(bsum, nb1024);
    scan_add<<<nb1024, 1024, 0, stream>>>(row_start, bsum, N, E);
    hipMemsetAsync(cnt, 0, N * sizeof(int), stream);
    scatter_edges<<<egrid, 256, 0, stream>>>(src, dst, E, row_start, cnt, sperm);

    // zero all 6 score arrays (contiguous)
    hipMemsetAsync(s1s, 0, (size_t)6 * N * sizeof(float), stream);

    // ---- layer 1 ----
    mfma_gemm_sc<<<dim3(mtiles, 2), 256, 0, stream>>>(xb, W1t, hlin, N, 256, 256,
                                                      a_src1, a_dst1, a_src1 + 128, a_dst1 + 128,
                                                      s1s, s1d, s1s, s1d);
    alpha_l1_kernel<<<ngrid256, 256, 0, stream>>>(s1s, s1d, row_start, sperm, alpha1, N);
    aggregate_l1<<<ngrid4, 256, 0, stream>>>(hlin, alpha1, row_start, sperm, b1, h, N);

    // ---- fused mu/logstd head ----
    mfma_gemm_sc<<<dim3(mtiles, 2), 256, 0, stream>>>(h, Wct, hcat, N, 256, 256,
                                                      a_src_mu, a_dst_mu, a_src_ls, a_dst_ls,
                                                      sms, smd, sls, sld);
    alpha_cat_kernel<<<ngrid256, 256, 0, stream>>>(sms, smd, sls, sld, row_start, sperm, amu, als, N);
    float* out_mu = (float*)d_out;
    float* out_ls = out_mu + (size_t)N * 128;
    aggregate_cat<<<ngrid4, 256, 0, stream>>>(hcat, amu, als, row_start, sperm,
                                              b_mu, b_ls, out_mu, out_ls, N);
}

// Round 4
// 430.499 us; speedup vs baseline: 1.0775x; 1.0775x over previous
//
#include <hip/hip_runtime.h>
#include <hip/hip_bf16.h>
#include <math.h>

// ---------------------------------------------------------------------------
// VariationalGATEncoder round 4:
//  - R3 post-mortem: pure-gather aggregate was a win (77->60us) but
//    thread-per-node 3-pass alpha kernels + GEMM score-epilogue atomics
//    cost ~+70us. Fixed here:
//  - alpha: wave-per-node, coalesced, single exp pass; stores UNNORMALIZED
//    p=exp(e-m) + per-node zinv; normalization folded into aggregate epilogue.
//  - scores: standalone round-2 kernels (coalesced bf16 row reads, ~8us).
//  - GEMM-1 converts x f32->bf16 on the fly in A-staging (removes convert
//    kernel's 77MB round trip).
//  - aggregate inner loop software-pipelined (explicit next-pair prefetch,
//    2 outstanding loads/wave) to attack latency-bound plateau.
// ---------------------------------------------------------------------------

#define NNODES 50000

typedef __attribute__((ext_vector_type(8))) short bf16x8;
typedef __attribute__((ext_vector_type(4))) float f32x4;

__device__ inline float bf2f(unsigned short u) {
    return __uint_as_float(((unsigned int)u) << 16);
}
__device__ inline unsigned short f2bf(float f) {
    unsigned int i = __float_as_uint(f);
    unsigned int r = i + 0x7fffu + ((i >> 16) & 1u);   // RNE
    return (unsigned short)(r >> 16);
}

// ---------------- weight transposes ----------------

__global__ void transpose_w_kernel(const float* __restrict__ W, unsigned short* __restrict__ Wt, int K, int Nc) {
    int n = blockIdx.x, k = threadIdx.x;
    Wt[(size_t)n * K + k] = f2bf(W[(size_t)k * Nc + n]);
}

__global__ void transpose_wcat_kernel(const float* __restrict__ Wmu, const float* __restrict__ Wls,
                                      unsigned short* __restrict__ Wt) {
    int n = blockIdx.x, k = threadIdx.x;
    float v = (n < 128) ? Wmu[(size_t)k * 128 + n] : Wls[(size_t)k * 128 + (n - 128)];
    Wt[(size_t)n * 256 + k] = f2bf(v);
}

// ---------------- CSR build ----------------

__global__ void count_edges(const int* __restrict__ dst, int E, int* __restrict__ cnt) {
    int e = blockIdx.x * blockDim.x + threadIdx.x;
    if (e < E) atomicAdd(&cnt[dst[e]], 1);
}

__global__ void scan_partial(const int* __restrict__ cnt, int* __restrict__ row_start,
                             int* __restrict__ bsum, int N) {
    __shared__ int wsum[16];
    int t = threadIdx.x;
    int gi = blockIdx.x * 1024 + t;
    int lane = t & 63, wid = t >> 6;
    int v = (gi < N) ? cnt[gi] : 0;
    int x = v;
    for (int off = 1; off < 64; off <<= 1) {
        int u = __shfl_up(x, off);
        if (lane >= off) x += u;
    }
    if (lane == 63) wsum[wid] = x;
    __syncthreads();
    if (wid == 0) {
        int s = (lane < 16) ? wsum[lane] : 0;
        for (int off = 1; off < 16; off <<= 1) {
            int u = __shfl_up(s, off);
            if (lane >= off) s += u;
        }
        if (lane < 16) wsum[lane] = s;
    }
    __syncthreads();
    int waveoff = (wid == 0) ? 0 : wsum[wid - 1];
    if (gi < N) row_start[gi] = waveoff + x - v;
    if (t == 1023) bsum[blockIdx.x] = waveoff + x;
}

__global__ void scan_bsum(int* __restrict__ bsum, int nb) {
    int lane = threadIdx.x;
    int v = (lane < nb) ? bsum[lane] : 0;
    int x = v;
    for (int off = 1; off < 64; off <<= 1) {
        int u = __shfl_up(x, off);
        if (lane >= off) x += u;
    }
    if (lane < nb) bsum[lane] = x - v;
}

__global__ void scan_add(int* __restrict__ row_start, const int* __restrict__ bsum, int N, int E) {
    int gi = blockIdx.x * 1024 + threadIdx.x;
    if (gi < N) row_start[gi] += bsum[blockIdx.x];
    if (gi == 0) row_start[N] = E;
}

__global__ void scatter_edges(const int* __restrict__ src, const int* __restrict__ dst, int E,
                              const int* __restrict__ row_start, int* __restrict__ cursor,
                              int* __restrict__ sperm) {
    int e = blockIdx.x * blockDim.x + threadIdx.x;
    if (e < E) {
        int d = dst[e];
        int pos = row_start[d] + atomicAdd(&cursor[d], 1);
        sperm[pos] = src[e];
    }
}

// ---------------- bf16 MFMA GEMM (plain) ----------------
// C[M,Cout](bf16) = A[M,K](bf16) @ Bt[Cout,K](bf16)^T, fp32 accumulate.

__global__ __launch_bounds__(256) void mfma_gemm(const unsigned short* __restrict__ A,
                                                 const unsigned short* __restrict__ Bt,
                                                 unsigned short* __restrict__ C_,
                                                 int M, int K, int Cout) {
    __shared__ __align__(16) unsigned short As[128 * 40];
    __shared__ __align__(16) unsigned short Bs[128 * 40];
    int t = threadIdx.x;
    int lane = t & 63, w = t >> 6;
    int wm = w & 1, wn = w >> 1;
    int l15 = lane & 15, quad = lane >> 4;
    int mbase = blockIdx.x * 128, nbase = blockIdx.y * 128;

    f32x4 acc[4][4];
    const f32x4 zero = {0.f, 0.f, 0.f, 0.f};
#pragma unroll
    for (int mt = 0; mt < 4; mt++)
#pragma unroll
        for (int nt = 0; nt < 4; nt++) acc[mt][nt] = zero;

    for (int k0 = 0; k0 < K; k0 += 32) {
#pragma unroll
        for (int i = t; i < 512; i += 256) {
            int row = i >> 2, seg = i & 3;
            int gr = mbase + row;
            float4 va = make_float4(0.f, 0.f, 0.f, 0.f);
            if (gr < M) va = *(const float4*)(A + (size_t)gr * K + k0 + seg * 8);
            *(float4*)(&As[row * 40 + seg * 8]) = va;
            float4 vb = *(const float4*)(Bt + (size_t)(nbase + row) * K + k0 + seg * 8);
            *(float4*)(&Bs[row * 40 + seg * 8]) = vb;
        }
        __syncthreads();
        bf16x8 af[4], bfr[4];
#pragma unroll
        for (int mt = 0; mt < 4; mt++)
            af[mt] = *(const bf16x8*)(&As[(wm * 64 + mt * 16 + l15) * 40 + quad * 8]);
#pragma unroll
        for (int nt = 0; nt < 4; nt++)
            bfr[nt] = *(const bf16x8*)(&Bs[(wn * 64 + nt * 16 + l15) * 40 + quad * 8]);
#pragma unroll
        for (int mt = 0; mt < 4; mt++)
#pragma unroll
            for (int nt = 0; nt < 4; nt++)
                acc[mt][nt] = __builtin_amdgcn_mfma_f32_16x16x32_bf16(af[mt], bfr[nt], acc[mt][nt], 0, 0, 0);
        __syncthreads();
    }
#pragma unroll
    for (int mt = 0; mt < 4; mt++)
#pragma unroll
        for (int nt = 0; nt < 4; nt++)
#pragma unroll
            for (int r = 0; r < 4; r++) {
                int m = mbase + wm * 64 + mt * 16 + quad * 4 + r;
                int n = nbase + wn * 64 + nt * 16 + l15;
                if (m < M) C_[(size_t)m * Cout + n] = f2bf(acc[mt][nt][r]);
            }
}

// Same GEMM but A is f32, converted to bf16 on the fly during staging.
__global__ __launch_bounds__(256) void mfma_gemm_xf32(const float* __restrict__ A,
                                                      const unsigned short* __restrict__ Bt,
                                                      unsigned short* __restrict__ C_,
                                                      int M, int K, int Cout) {
    __shared__ __align__(16) unsigned short As[128 * 40];
    __shared__ __align__(16) unsigned short Bs[128 * 40];
    int t = threadIdx.x;
    int lane = t & 63, w = t >> 6;
    int wm = w & 1, wn = w >> 1;
    int l15 = lane & 15, quad = lane >> 4;
    int mbase = blockIdx.x * 128, nbase = blockIdx.y * 128;

    f32x4 acc[4][4];
    const f32x4 zero = {0.f, 0.f, 0.f, 0.f};
#pragma unroll
    for (int mt = 0; mt < 4; mt++)
#pragma unroll
        for (int nt = 0; nt < 4; nt++) acc[mt][nt] = zero;

    for (int k0 = 0; k0 < K; k0 += 32) {
#pragma unroll
        for (int i = t; i < 512; i += 256) {
            int row = i >> 2, seg = i & 3;
            int gr = mbase + row;
            float4 a0 = make_float4(0.f, 0.f, 0.f, 0.f), a1 = a0;
            if (gr < M) {
                const float* ap = A + (size_t)gr * K + k0 + seg * 8;
                a0 = *(const float4*)ap;
                a1 = *(const float4*)(ap + 4);
            }
            ushort4 lo, hi;
            lo.x = f2bf(a0.x); lo.y = f2bf(a0.y); lo.z = f2bf(a0.z); lo.w = f2bf(a0.w);
            hi.x = f2bf(a1.x); hi.y = f2bf(a1.y); hi.z = f2bf(a1.z); hi.w = f2bf(a1.w);
            *(ushort4*)(&As[row * 40 + seg * 8]) = lo;
            *(ushort4*)(&As[row * 40 + seg * 8 + 4]) = hi;
            float4 vb = *(const float4*)(Bt + (size_t)(nbase + row) * K + k0 + seg * 8);
            *(float4*)(&Bs[row * 40 + seg * 8]) = vb;
        }
        __syncthreads();
        bf16x8 af[4], bfr[4];
#pragma unroll
        for (int mt = 0; mt < 4; mt++)
            af[mt] = *(const bf16x8*)(&As[(wm * 64 + mt * 16 + l15) * 40 + quad * 8]);
#pragma unroll
        for (int nt = 0; nt < 4; nt++)
            bfr[nt] = *(const bf16x8*)(&Bs[(wn * 64 + nt * 16 + l15) * 40 + quad * 8]);
#pragma unroll
        for (int mt = 0; mt < 4; mt++)
#pragma unroll
            for (int nt = 0; nt < 4; nt++)
                acc[mt][nt] = __builtin_amdgcn_mfma_f32_16x16x32_bf16(af[mt], bfr[nt], acc[mt][nt], 0, 0, 0);
        __syncthreads();
    }
#pragma unroll
    for (int mt = 0; mt < 4; mt++)
#pragma unroll
        for (int nt = 0; nt < 4; nt++)
#pragma unroll
            for (int r = 0; r < 4; r++) {
                int m = mbase + wm * 64 + mt * 16 + quad * 4 + r;
                int n = nbase + wn * 64 + nt * 16 + l15;
                if (m < M) C_[(size_t)m * Cout + n] = f2bf(acc[mt][nt][r]);
            }
}

// ---------------- scores (round-2 style, coalesced) ----------------

__global__ __launch_bounds__(256) void scores_l1(const unsigned short* __restrict__ h,
                                                 const float* __restrict__ a_src,
                                                 const float* __restrict__ a_dst,
                                                 float* __restrict__ ssrc,
                                                 float* __restrict__ sdst, int N) {
    int wave = threadIdx.x >> 6, lane = threadIdx.x & 63;
    int row = blockIdx.x * 4 + wave;
    if (row >= N) return;
    ushort4 u = *(const ushort4*)(h + (size_t)row * 256 + lane * 4);
    float h0 = bf2f(u.x), h1 = bf2f(u.y), h2 = bf2f(u.z), h3 = bf2f(u.w);
    float4 av = ((const float4*)a_src)[lane];
    float4 dv = ((const float4*)a_dst)[lane];
    float ss = h0 * av.x + h1 * av.y + h2 * av.z + h3 * av.w;
    float sd = h0 * dv.x + h1 * dv.y + h2 * dv.z + h3 * dv.w;
    for (int off = 32; off; off >>= 1) {
        ss += __shfl_xor(ss, off);
        sd += __shfl_xor(sd, off);
    }
    if (lane == 0) {
        ssrc[row] = ss;
        sdst[row] = sd;
    }
}

__global__ __launch_bounds__(256) void scores_cat(const unsigned short* __restrict__ hcat,
                                                  const float* __restrict__ a_src_mu, const float* __restrict__ a_dst_mu,
                                                  const float* __restrict__ a_src_ls, const float* __restrict__ a_dst_ls,
                                                  float* __restrict__ sm_s, float* __restrict__ sm_d,
                                                  float* __restrict__ sl_s, float* __restrict__ sl_d, int N) {
    int wave = threadIdx.x >> 6, lane = threadIdx.x & 63;
    int row = blockIdx.x * 4 + wave;
    if (row >= N) return;
    ushort4 u = *(const ushort4*)(hcat + (size_t)row * 256 + lane * 4);
    float h0 = bf2f(u.x), h1 = bf2f(u.y), h2 = bf2f(u.z), h3 = bf2f(u.w);
    bool isMu = lane < 32;
    const float* as = isMu ? a_src_mu : a_src_ls;
    const float* ad = isMu ? a_dst_mu : a_dst_ls;
    int c = (lane & 31) * 4;
    float4 av = *(const float4*)(as + c);
    float4 dv = *(const float4*)(ad + c);
    float ss = h0 * av.x + h1 * av.y + h2 * av.z + h3 * av.w;
    float sd = h0 * dv.x + h1 * dv.y + h2 * dv.z + h3 * dv.w;
    for (int off = 16; off; off >>= 1) {
        ss += __shfl_xor(ss, off);
        sd += __shfl_xor(sd, off);
    }
    if ((lane & 31) == 0) {
        if (isMu) { sm_s[row] = ss; sm_d[row] = sd; }
        else      { sl_s[row] = ss; sl_d[row] = sd; }
    }
}

// ---------------- alpha: wave-per-node, unnormalized p + zinv ----------------

__global__ __launch_bounds__(256) void alpha_l1_kernel(const float* __restrict__ ssrc,
                                                       const float* __restrict__ sdst,
                                                       const int* __restrict__ row_start,
                                                       const int* __restrict__ sperm,
                                                       float* __restrict__ p,
                                                       float* __restrict__ zinv, int N) {
    int wave = threadIdx.x >> 6, lane = threadIdx.x & 63;
    int node = blockIdx.x * 4 + wave;
    if (node >= N) return;
    int b = row_start[node], e = row_start[node + 1];
    float sd = sdst[node];
    float m = -INFINITY;
    for (int j0 = b; j0 < e; j0 += 64) {
        int idx = j0 + lane;
        if (idx < e) {
            float t = ssrc[sperm[idx]] + sd;
            t = (t > 0.f) ? t : 0.2f * t;
            m = fmaxf(m, t);
        }
    }
    for (int off = 32; off; off >>= 1) m = fmaxf(m, __shfl_xor(m, off));
    float z = 0.f;
    for (int j0 = b; j0 < e; j0 += 64) {
        int idx = j0 + lane;
        if (idx < e) {
            float t = ssrc[sperm[idx]] + sd;
            t = (t > 0.f) ? t : 0.2f * t;
            float pv = __expf(t - m);
            p[idx] = pv;
            z += pv;
        }
    }
    for (int off = 32; off; off >>= 1) z += __shfl_xor(z, off);
    if (lane == 0) zinv[node] = 1.f / (z + 1e-16f);
}

__global__ __launch_bounds__(256) void alpha_cat_kernel(const float* __restrict__ sms,
                                                        const float* __restrict__ smd,
                                                        const float* __restrict__ sls,
                                                        const float* __restrict__ sld,
                                                        const int* __restrict__ row_start,
                                                        const int* __restrict__ sperm,
                                                        float* __restrict__ pmu, float* __restrict__ pls,
                                                        float* __restrict__ zim, float* __restrict__ zil, int N) {
    int wave = threadIdx.x >> 6, lane = threadIdx.x & 63;
    int node = blockIdx.x * 4 + wave;
    if (node >= N) return;
    int b = row_start[node], e = row_start[node + 1];
    float sdm = smd[node], sdl = sld[node];
    float mM = -INFINITY, mL = -INFINITY;
    for (int j0 = b; j0 < e; j0 += 64) {
        int idx = j0 + lane;
        if (idx < e) {
            int s = sperm[idx];
            float tM = sms[s] + sdm;
            tM = (tM > 0.f) ? tM : 0.2f * tM;
            mM = fmaxf(mM, tM);
            float tL = sls[s] + sdl;
            tL = (tL > 0.f) ? tL : 0.2f * tL;
            mL = fmaxf(mL, tL);
        }
    }
    for (int off = 32; off; off >>= 1) {
        mM = fmaxf(mM, __shfl_xor(mM, off));
        mL = fmaxf(mL, __shfl_xor(mL, off));
    }
    float zM = 0.f, zL = 0.f;
    for (int j0 = b; j0 < e; j0 += 64) {
        int idx = j0 + lane;
        if (idx < e) {
            int s = sperm[idx];
            float tM = sms[s] + sdm;
            tM = (tM > 0.f) ? tM : 0.2f * tM;
            float pM = __expf(tM - mM);
            pmu[idx] = pM;
            zM += pM;
            float tL = sls[s] + sdl;
            tL = (tL > 0.f) ? tL : 0.2f * tL;
            float pL = __expf(tL - mL);
            pls[idx] = pL;
            zL += pL;
        }
    }
    for (int off = 32; off; off >>= 1) {
        zM += __shfl_xor(zM, off);
        zL += __shfl_xor(zL, off);
    }
    if (lane == 0) {
        zim[node] = 1.f / (zM + 1e-16f);
        zil[node] = 1.f / (zL + 1e-16f);
    }
}

// ---------------- aggregation: weighted gather, software-pipelined ----------------

__device__ inline void cvt2(unsigned int d, float& lo, float& hi) {
    lo = __uint_as_float(d << 16);
    hi = __uint_as_float(d & 0xffff0000u);
}

__device__ inline void fma8(float* acc, uint4 d, float w) {
    float f0, f1, f2, f3, f4, f5, f6, f7;
    cvt2(d.x, f0, f1); cvt2(d.y, f2, f3); cvt2(d.z, f4, f5); cvt2(d.w, f6, f7);
    acc[0] += w * f0; acc[1] += w * f1; acc[2] += w * f2; acc[3] += w * f3;
    acc[4] += w * f4; acc[5] += w * f5; acc[6] += w * f6; acc[7] += w * f7;
}

__global__ __launch_bounds__(256) void aggregate_l1(const unsigned short* __restrict__ h,
                                                    const float* __restrict__ p,
                                                    const float* __restrict__ zinv,
                                                    const int* __restrict__ row_start,
                                                    const int* __restrict__ sperm,
                                                    const float* __restrict__ bias,
                                                    unsigned short* __restrict__ out, int N) {
    int wave = threadIdx.x >> 6, lane = threadIdx.x & 63;
    int node = blockIdx.x * 4 + wave;
    if (node >= N) return;
    int begin = row_start[node], end = row_start[node + 1];
    int half = lane >> 5, l31 = lane & 31;
    float acc[8];
#pragma unroll
    for (int u = 0; u < 8; u++) acc[u] = 0.f;

    for (int j0 = begin; j0 < end; j0 += 64) {
        int idx = j0 + lane;
        bool v = idx < end;
        float a_l = v ? p[idx] : 0.f;
        int s_l = v ? sperm[idx] : 0;
        int cnt = min(64, end - j0);
        int iters = (cnt + 1) >> 1;
        // software pipeline: 2 outstanding loads
        int t0 = half;
        int tc = min(t0, cnt - 1);
        float w_c = __shfl(a_l, tc);
        if (t0 >= cnt) w_c = 0.f;
        int s_c = __shfl(s_l, tc);
        uint4 d_c = *((const uint4*)(h + (size_t)s_c * 256) + l31);
        for (int i = 1; i < iters; i++) {
            int t = 2 * i + half;
            int tc2 = min(t, cnt - 1);
            float w_n = __shfl(a_l, tc2);
            if (t >= cnt) w_n = 0.f;
            int s_n = __shfl(s_l, tc2);
            uint4 d_n = *((const uint4*)(h + (size_t)s_n * 256) + l31);
            fma8(acc, d_c, w_c);
            w_c = w_n; d_c = d_n;
        }
        fma8(acc, d_c, w_c);
    }
#pragma unroll
    for (int u = 0; u < 8; u++) acc[u] += __shfl_xor(acc[u], 32);
    if (half == 0) {
        float zi = zinv[node];
        int c = l31 * 8;
        float4 b0 = *(const float4*)(bias + c);
        float4 b1 = *(const float4*)(bias + c + 4);
        float o0 = fmaxf(acc[0] * zi + b0.x, 0.f), o1 = fmaxf(acc[1] * zi + b0.y, 0.f);
        float o2 = fmaxf(acc[2] * zi + b0.z, 0.f), o3 = fmaxf(acc[3] * zi + b0.w, 0.f);
        float o4 = fmaxf(acc[4] * zi + b1.x, 0.f), o5 = fmaxf(acc[5] * zi + b1.y, 0.f);
        float o6 = fmaxf(acc[6] * zi + b1.z, 0.f), o7 = fmaxf(acc[7] * zi + b1.w, 0.f);
        uint4 st;
        st.x = ((unsigned)f2bf(o1) << 16) | f2bf(o0);
        st.y = ((unsigned)f2bf(o3) << 16) | f2bf(o2);
        st.z = ((unsigned)f2bf(o5) << 16) | f2bf(o4);
        st.w = ((unsigned)f2bf(o7) << 16) | f2bf(o6);
        *(uint4*)(out + (size_t)node * 256 + c) = st;
    }
}

__global__ __launch_bounds__(256) void aggregate_cat(const unsigned short* __restrict__ hcat,
                                                     const float* __restrict__ pmu,
                                                     const float* __restrict__ pls,
                                                     const float* __restrict__ zim,
                                                     const float* __restrict__ zil,
                                                     const int* __restrict__ row_start,
                                                     const int* __restrict__ sperm,
                                                     const float* __restrict__ b_mu,
                                                     const float* __restrict__ b_ls,
                                                     float* __restrict__ out_mu,
                                                     float* __restrict__ out_ls, int N) {
    int wave = threadIdx.x >> 6, lane = threadIdx.x & 63;
    int node = blockIdx.x * 4 + wave;
    if (node >= N) return;
    int begin = row_start[node], end = row_start[node + 1];
    int half = lane >> 5, l31 = lane & 31;
    bool isMu = l31 < 16;
    float acc[8];
#pragma unroll
    for (int u = 0; u < 8; u++) acc[u] = 0.f;

    for (int j0 = begin; j0 < end; j0 += 64) {
        int idx = j0 + lane;
        bool v = idx < end;
        float am_l = v ? pmu[idx] : 0.f;
        float al_l = v ? pls[idx] : 0.f;
        int s_l = v ? sperm[idx] : 0;
        int cnt = min(64, end - j0);
        int iters = (cnt + 1) >> 1;
        int t0 = half;
        int tc = min(t0, cnt - 1);
        float wm_c = __shfl(am_l, tc);
        float wl_c = __shfl(al_l, tc);
        float w_c = isMu ? wm_c : wl_c;
        if (t0 >= cnt) w_c = 0.f;
        int s_c = __shfl(s_l, tc);
        uint4 d_c = *((const uint4*)(hcat + (size_t)s_c * 256) + l31);
        for (int i = 1; i < iters; i++) {
            int t = 2 * i + half;
            int tc2 = min(t, cnt - 1);
            float wm_n = __shfl(am_l, tc2);
            float wl_n = __shfl(al_l, tc2);
            float w_n = isMu ? wm_n : wl_n;
            if (t >= cnt) w_n = 0.f;
            int s_n = __shfl(s_l, tc2);
            uint4 d_n = *((const uint4*)(hcat + (size_t)s_n * 256) + l31);
            fma8(acc, d_c, w_c);
            w_c = w_n; d_c = d_n;
        }
        fma8(acc, d_c, w_c);
    }
#pragma unroll
    for (int u = 0; u < 8; u++) acc[u] += __shfl_xor(acc[u], 32);
    if (half == 0) {
        float zi = isMu ? zim[node] : zil[node];
        int c = isMu ? (l31 * 8) : (l31 * 8 - 128);
        const float* bp = isMu ? b_mu : b_ls;
        float* op = isMu ? out_mu : out_ls;
        float4 b0 = *(const float4*)(bp + c);
        float4 b1 = *(const float4*)(bp + c + 4);
        float4 v0 = make_float4(acc[0] * zi + b0.x, acc[1] * zi + b0.y,
                                acc[2] * zi + b0.z, acc[3] * zi + b0.w);
        float4 v1 = make_float4(acc[4] * zi + b1.x, acc[5] * zi + b1.y,
                                acc[6] * zi + b1.z, acc[7] * zi + b1.w);
        *(float4*)(op + (size_t)node * 128 + c) = v0;
        *(float4*)(op + (size_t)node * 128 + c + 4) = v1;
    }
}

// ---------------- launch ----------------

extern "C" void kernel_launch(void* const* d_in, const int* in_sizes, int n_in,
                              void* d_out, int out_size, void* d_ws, size_t ws_size,
                              hipStream_t stream) {
    const int N = NNODES;
    const float* x      = (const float*)d_in[0];
    const int*   ei     = (const int*)d_in[1];
    const int    E      = in_sizes[1] / 2;
    const int*   src    = ei;
    const int*   dst    = ei + E;
    const float* W1     = (const float*)d_in[2];
    const float* a_src1 = (const float*)d_in[3];
    const float* a_dst1 = (const float*)d_in[4];
    const float* b1     = (const float*)d_in[5];
    const float* W_mu   = (const float*)d_in[6];
    const float* a_src_mu = (const float*)d_in[7];
    const float* a_dst_mu = (const float*)d_in[8];
    const float* b_mu   = (const float*)d_in[9];
    const float* W_ls   = (const float*)d_in[10];
    const float* a_src_ls = (const float*)d_in[11];
    const float* a_dst_ls = (const float*)d_in[12];
    const float* b_ls   = (const float*)d_in[13];

    const size_t NM = (size_t)N * 256;

    // workspace layout
    char* w = (char*)d_ws;
    unsigned short* hlin = (unsigned short*)w;  w += NM * 2;
    unsigned short* h    = (unsigned short*)w;  w += NM * 2;
    unsigned short* hcat = (unsigned short*)w;  w += NM * 2;
    unsigned short* W1t  = (unsigned short*)w;  w += 256 * 256 * 2;
    unsigned short* Wct  = (unsigned short*)w;  w += 256 * 256 * 2;
    float* s1s = (float*)w;  w += N * 4;
    float* s1d = (float*)w;  w += N * 4;
    float* sms = (float*)w;  w += N * 4;
    float* smd = (float*)w;  w += N * 4;
    float* sls = (float*)w;  w += N * 4;
    float* sld = (float*)w;  w += N * 4;
    float* zi1 = (float*)w;  w += N * 4;
    float* zim = (float*)w;  w += N * 4;
    float* zil = (float*)w;  w += N * 4;
    float* p1  = (float*)w;  w += (size_t)E * 4;
    float* pmu = (float*)w;  w += (size_t)E * 4;
    float* pls = (float*)w;  w += (size_t)E * 4;
    int* row_start = (int*)w;  w += (N + 1) * 4;
    int* cnt = (int*)w;        w += N * 4;
    int* bsum = (int*)w;       w += 64 * 4;
    int* sperm = (int*)w;      w += (size_t)E * 4;

    const int egrid = (E + 255) / 256;
    const int ngrid4 = (N + 3) / 4;               // 12500
    const int nb1024 = (N + 1023) / 1024;         // 49
    const int mtiles = (N + 127) / 128;           // 391

    // ---- weight transposes ----
    transpose_w_kernel<<<256, 256, 0, stream>>>(W1, W1t, 256, 256);
    transpose_wcat_kernel<<<256, 256, 0, stream>>>(W_mu, W_ls, Wct);

    // ---- CSR build ----
    hipMemsetAsync(cnt, 0, N * sizeof(int), stream);
    count_edges<<<egrid, 256, 0, stream>>>(dst, E, cnt);
    scan_partial<<<nb1024, 1024, 0, stream>>>(cnt, row_start, bsum, N);
    scan_bsum<<<1, 64, 0, stream>>>(bsum, nb1024);
    scan_add<<<nb1024, 1024, 0, stream>>>(row_start, bsum, N, E);
    hipMemsetAsync(cnt, 0, N * sizeof(int), stream);
    scatter_edges<<<egrid, 256, 0, stream>>>(src, dst, E, row_start, cnt, sperm);

    // ---- layer 1 ----
    mfma_gemm_xf32<<<dim3(mtiles, 2), 256, 0, stream>>>(x, W1t, hlin, N, 256, 256);
    scores_l1<<<ngrid4, 256, 0, stream>>>(hlin, a_src1, a_dst1, s1s, s1d, N);
    alpha_l1_kernel<<<ngrid4, 256, 0, stream>>>(s1s, s1d, row_start, sperm, p1, zi1, N);
    aggregate_l1<<<ngrid4, 256, 0, stream>>>(hlin, p1, zi1, row_start, sperm, b1, h, N);

    // ---- fused mu/logstd head ----
    mfma_gemm<<<dim3(mtiles, 2), 256, 0, stream>>>(h, Wct, hcat, N, 256, 256);
    scores_cat<<<ngrid4, 256, 0, stream>>>(hcat, a_src_mu, a_dst_mu, a_src_ls, a_dst_ls,
                                           sms, smd, sls, sld, N);
    alpha_cat_kernel<<<ngrid4, 256, 0, stream>>>(sms, smd, sls, sld, row_start, sperm,
                                                 pmu, pls, zim, zil, N);
    float* out_mu = (float*)d_out;
    float* out_ls = out_mu + (size_t)N * 128;
    aggregate_cat<<<ngrid4, 256, 0, stream>>>(hcat, pmu, pls, zim, zil, row_start, sperm,
                                              b_mu, b_ls, out_mu, out_ls, N);
}